// Round 2
// baseline (84.326 us; speedup 1.0000x reference)
//
#include <hip/hip_runtime.h>
#include <hip/hip_bf16.h>

#define NROWS 8192
#define DDIM  128
#define NKCH  64                    // n-chunks of 128
#define CHN   128                   // n per chunk
#define NPAIR 10                    // triangular (ti<=tj) over 4 dim-groups of 64
#define NGRP  16                    // chunk-groups per pair
#define CPG   4                     // chunks accumulated per block (K=512)
#define K2_BLOCKS (NPAIR * NGRP)    // 160
#define NPAD1 18                    // norm LDS column-major pitch in shorts (9 dwords, coprime 32)

typedef unsigned short ushort_t;
typedef unsigned int   uint_t;
typedef __attribute__((ext_vector_type(8))) short short8;
typedef __attribute__((ext_vector_type(4))) float floatx4;

#define LDS_PTR(p) ((__attribute__((address_space(3))) void*)(p))
#define GLB_PTR(p) ((const __attribute__((address_space(1))) void*)(p))

// round-to-nearest-even fp32 -> bf16 bits
static __device__ inline ushort_t f2bf(float f) {
    union { float f; uint_t u; } a; a.f = f;
    uint_t u = a.u + 0x7fffu + ((a.u >> 16) & 1u);
    return (ushort_t)(u >> 16);
}

// decode triangular pair p -> (ti,tj), ti<=tj over 4 groups
static __device__ inline void pair_decode(int p, int* ti, int* tj) {
    int i = 0, len = 4;
    while (p >= len) { p -= len; len--; i++; }
    *ti = i; *tj = i + p;
}

// K1: row-normalize q,k -> bf16, write BLOCKED transposed Gt:
// layout [c:64][dim:256][n:128], dim<128 = Qn, dim>=128 = Kn.
// 512 blocks x 16 n-rows (2 blocks/CU -> 2 waves/SIMD for latency hiding).
// Also zeroes M (40960 floats, workspace is poisoned) and the counter.
__global__ __launch_bounds__(256) void norm_t_kernel(
    const float* __restrict__ q, const float* __restrict__ k,
    ushort_t* __restrict__ Gt, float* __restrict__ M, uint_t* counter)
{
    __shared__ ushort_t lds[256 * NPAD1];   // 9.2 KB: [dim][n-local 16]
    if (blockIdx.x < K2_BLOCKS) M[blockIdx.x * 256 + threadIdx.x] = 0.f;
    if (blockIdx.x == 0 && threadIdx.x == 0) *counter = 0u;

    int b   = blockIdx.x;        // 512 blocks x 16 rows
    int c   = b >> 3;            // chunk 0..63
    int sub = b & 7;             // 16-row eighth of the chunk
    int w   = threadIdx.x >> 6;
    int l   = threadIdx.x & 63;
    int h   = l >> 5;            // half-wave: row parity
    int li  = l & 31;            // lane in half: 4 dims each

    #pragma unroll
    for (int i = 0; i < 2; ++i) {
        int rl  = i * 8 + w * 2 + h;             // local n-row 0..15
        int row = b * 16 + rl;
        {
            float4 v = ((const float4*)(q + (size_t)row * DDIM))[li];
            float ss = v.x * v.x + v.y * v.y + v.z * v.z + v.w * v.w;
            #pragma unroll
            for (int o = 16; o > 0; o >>= 1) ss += __shfl_xor(ss, o, 64);
            float inv = rsqrtf(fmaxf(ss, 1e-16f));
            lds[(4 * li + 0) * NPAD1 + rl] = f2bf(v.x * inv);
            lds[(4 * li + 1) * NPAD1 + rl] = f2bf(v.y * inv);
            lds[(4 * li + 2) * NPAD1 + rl] = f2bf(v.z * inv);
            lds[(4 * li + 3) * NPAD1 + rl] = f2bf(v.w * inv);
        }
        {
            float4 v = ((const float4*)(k + (size_t)row * DDIM))[li];
            float ss = v.x * v.x + v.y * v.y + v.z * v.z + v.w * v.w;
            #pragma unroll
            for (int o = 16; o > 0; o >>= 1) ss += __shfl_xor(ss, o, 64);
            float inv = rsqrtf(fmaxf(ss, 1e-16f));
            lds[(128 + 4 * li + 0) * NPAD1 + rl] = f2bf(v.x * inv);
            lds[(128 + 4 * li + 1) * NPAD1 + rl] = f2bf(v.y * inv);
            lds[(128 + 4 * li + 2) * NPAD1 + rl] = f2bf(v.z * inv);
            lds[(128 + 4 * li + 3) * NPAD1 + rl] = f2bf(v.w * inv);
        }
    }
    __syncthreads();

    // phase 2: thread owns dim a; vector-read its 16 n (8 x b32, 4B-aligned,
    // 9-dword pitch -> conflict-free), store 32 B contiguous into blocked Gt.
    int a = threadIdx.x;
    union { uint_t u32[8]; uint4 v4[2]; } tb;
    #pragma unroll
    for (int t = 0; t < 8; ++t)
        tb.u32[t] = *(const uint_t*)&lds[a * NPAD1 + 2 * t];

    char* gdst = (char*)Gt + (size_t)(c * 256 + a) * (CHN * 2) + sub * 32;
    *(uint4*)(gdst)      = tb.v4[0];
    *(uint4*)(gdst + 16) = tb.v4[1];
}

// K2: register-accumulated partial Gram (R7-verified MFMA body, XOR-swizzled
// LDS). 10 pairs x 16 groups = 160 blocks; each block accumulates CPG=4
// chunks (K=512) in MFMA registers with double-buffered global_load_lds
// staging, then fp32-atomicAdds its 64x64 partial into M[pair]. The
// counter-elected last block weights/squares/fp64-reduces M -> out.
__global__ __launch_bounds__(128) void gram_acc_kernel(
    const ushort_t* __restrict__ Gt, float* __restrict__ M,
    uint_t* __restrict__ counter, float* __restrict__ out)
{
    __shared__ ushort_t sA[2][64 * CHN];   // 2 x 16 KB
    __shared__ ushort_t sB[2][64 * CHN];   // 2 x 16 KB
    __shared__ double dred[2];
    __shared__ uint_t isLast;

    int pair = blockIdx.x >> 4;         // 0..9
    int g    = blockIdx.x & 15;         // chunk-group
    int ti, tj;
    pair_decode(pair, &ti, &tj);
    int tid = threadIdx.x;
    int c0  = g * CPG;

    auto stage = [&](int buf, int c) {
        const char* gA = (const char*)Gt + (size_t)(c * 256 + ti * 64) * (CHN * 2);
        const char* gB = (const char*)Gt + (size_t)(c * 256 + tj * 64) * (CHN * 2);
        #pragma unroll
        for (int it = 0; it < 8; ++it) {
            int ch = it * 128 + tid;               // 0..1023
            int row = ch >> 4, phys = ch & 15;
            int logical = phys ^ (row & 7);
            __builtin_amdgcn_global_load_lds(GLB_PTR(gA + row * 256 + logical * 16),
                                             LDS_PTR((char*)sA[buf] + ch * 16), 16, 0, 0);
        }
        #pragma unroll
        for (int it = 0; it < 8; ++it) {
            int ch = it * 128 + tid;
            int row = ch >> 4, phys = ch & 15;
            int logical = phys ^ (row & 7);
            __builtin_amdgcn_global_load_lds(GLB_PTR(gB + row * 256 + logical * 16),
                                             LDS_PTR((char*)sB[buf] + ch * 16), 16, 0, 0);
        }
    };

    int w    = tid >> 6;        // a-strip: rows w*32..w*32+31
    int l    = tid & 63;
    int m    = l & 15;
    int quad = l >> 4;

    floatx4 accC[2][4];
    #pragma unroll
    for (int at = 0; at < 2; ++at)
        #pragma unroll
        for (int bt = 0; bt < 4; ++bt)
            accC[at][bt] = (floatx4){0.f, 0.f, 0.f, 0.f};

    stage(0, c0);
    __syncthreads();

    #pragma unroll
    for (int j = 0; j < CPG; ++j) {
        if (j + 1 < CPG) stage((j + 1) & 1, c0 + j + 1);   // prefetch overlaps MFMA
        const ushort_t* cA = sA[j & 1];
        const ushort_t* cB = sB[j & 1];
        #pragma unroll
        for (int kp = 0; kp < 4; ++kp) {
            short8 af[2], bf[4];
            #pragma unroll
            for (int at = 0; at < 2; ++at) {
                int ra   = w * 32 + at * 16 + m;
                int phys = (kp * 4 + quad) ^ (ra & 7);
                af[at] = *(const short8*)&cA[ra * CHN + phys * 8];
            }
            #pragma unroll
            for (int bt = 0; bt < 4; ++bt) {
                int rb   = bt * 16 + m;
                int phys = (kp * 4 + quad) ^ (rb & 7);
                bf[bt] = *(const short8*)&cB[rb * CHN + phys * 8];
            }
            #pragma unroll
            for (int at = 0; at < 2; ++at)
                #pragma unroll
                for (int bt = 0; bt < 4; ++bt)
                    accC[at][bt] = __builtin_amdgcn_mfma_f32_16x16x32_bf16(af[at], bf[bt], accC[at][bt], 0, 0, 0);
        }
        __syncthreads();
    }

    // accumulate 64x64 fp32 partial into M[pair] (16-way contention)
    float* mp = M + (size_t)pair * 4096;
    #pragma unroll
    for (int at = 0; at < 2; ++at)
        #pragma unroll
        for (int bt = 0; bt < 4; ++bt)
            #pragma unroll
            for (int r = 0; r < 4; ++r) {
                int row = w * 32 + at * 16 + quad * 4 + r;
                int col = bt * 16 + m;
                atomicAdd(&mp[row * 64 + col], accC[at][bt][r]);
            }

    __syncthreads();                 // drains every thread's atomics (vmcnt 0)
    if (tid == 0) {
        __threadfence();             // release
        uint_t old = atomicAdd(counter, 1u);
        isLast = (old == K2_BLOCKS - 1) ? 1u : 0u;
    }
    __syncthreads();

    if (isLast) {
        __threadfence();             // acquire
        // weights: +1 same-side diag, +/-2 off-diag (symmetric tile x2), - cross
        const float WGTS[NPAIR] = {1.f, 2.f, -2.f, -2.f, 1.f, -2.f, -2.f, 1.f, 2.f, 1.f};
        double tacc = 0.0;
        #pragma unroll
        for (int p = 0; p < NPAIR; ++p) {
            float wp = WGTS[p];
            #pragma unroll 8
            for (int ii = 0; ii < 32; ++ii) {
                float s = __hip_atomic_load(&M[p * 4096 + ii * 128 + tid],
                                            __ATOMIC_RELAXED, __HIP_MEMORY_SCOPE_AGENT);
                tacc += (double)(wp * s * s);
            }
        }
        #pragma unroll
        for (int o = 32; o > 0; o >>= 1) tacc += __shfl_xor(tacc, o, 64);
        if (l == 0) dred[w] = tacc;
        __syncthreads();
        if (tid == 0)
            out[0] = (float)((dred[0] + dred[1]) *
                             (1.0 / ((double)NROWS * (double)(NROWS - 1))));
    }
}

extern "C" void kernel_launch(void* const* d_in, const int* in_sizes, int n_in,
                              void* d_out, int out_size, void* d_ws, size_t ws_size,
                              hipStream_t stream) {
    const float* q = (const float*)d_in[0];
    const float* k = (const float*)d_in[1];
    float* out = (float*)d_out;

    uint_t*   cnt = (uint_t*)d_ws;
    float*    M   = (float*)((char*)d_ws + 256);                       // 160 KB
    ushort_t* Gt  = (ushort_t*)((char*)d_ws + 256 + NPAIR * 4096 * 4); // 4 MB blocked

    norm_t_kernel<<<NROWS / 16, 256, 0, stream>>>(q, k, Gt, M, cnt);
    gram_acc_kernel<<<K2_BLOCKS, 128, 0, stream>>>(Gt, M, cnt, out);
}

// Round 3
// 72.335 us; speedup vs baseline: 1.1658x; 1.1658x over previous
//
#include <hip/hip_runtime.h>
#include <hip/hip_bf16.h>

#define NROWS 8192
#define DDIM  128
#define NKCH  64                    // n-chunks of 128
#define CHN   128                   // n per chunk
#define NPAIR 10                    // triangular (ti<=tj) over 4 dim-groups of 64
#define NGRP  32                    // chunk-groups per pair
#define CPG   2                     // chunks accumulated per block (K=256)
#define K2_BLOCKS (NPAIR * NGRP)    // 320
#define GB_BLOCKS 160               // gram_b grid (10*4096/256)
#define NPAD1 18                    // norm LDS column-major pitch in shorts (9 dwords, coprime 32)

typedef unsigned short ushort_t;
typedef unsigned int   uint_t;
typedef __attribute__((ext_vector_type(8))) short short8;
typedef __attribute__((ext_vector_type(4))) float floatx4;

#define LDS_PTR(p) ((__attribute__((address_space(3))) void*)(p))
#define GLB_PTR(p) ((const __attribute__((address_space(1))) void*)(p))

// round-to-nearest-even fp32 -> bf16 bits
static __device__ inline ushort_t f2bf(float f) {
    union { float f; uint_t u; } a; a.f = f;
    uint_t u = a.u + 0x7fffu + ((a.u >> 16) & 1u);
    return (ushort_t)(u >> 16);
}

// decode triangular pair p -> (ti,tj), ti<=tj over 4 groups
static __device__ inline void pair_decode(int p, int* ti, int* tj) {
    int i = 0, len = 4;
    while (p >= len) { p -= len; len--; i++; }
    *ti = i; *tj = i + p;
}

// K1: row-normalize q,k -> bf16, write BLOCKED transposed Gt:
// layout [c:64][dim:256][n:128], dim<128 = Qn, dim>=128 = Kn.
// 512 blocks x 16 n-rows (2 blocks/CU -> 2x latency hiding vs 256-block ver).
__global__ __launch_bounds__(256) void norm_t_kernel(
    const float* __restrict__ q, const float* __restrict__ k,
    ushort_t* __restrict__ Gt, double* acc, uint_t* counter)
{
    __shared__ ushort_t lds[256 * NPAD1];   // 9.2 KB: [dim][n-local 16]
    if (blockIdx.x == 0 && threadIdx.x == 0) { *acc = 0.0; *counter = 0u; }

    int b   = blockIdx.x;        // 512 blocks x 16 rows
    int c   = b >> 3;            // chunk 0..63
    int sub = b & 7;             // 16-row eighth of the chunk
    int w   = threadIdx.x >> 6;
    int l   = threadIdx.x & 63;
    int h   = l >> 5;            // half-wave: row parity
    int li  = l & 31;            // lane in half: 4 dims each

    #pragma unroll
    for (int i = 0; i < 2; ++i) {
        int rl  = i * 8 + w * 2 + h;             // local n-row 0..15
        int row = b * 16 + rl;
        {
            float4 v = ((const float4*)(q + (size_t)row * DDIM))[li];
            float ss = v.x * v.x + v.y * v.y + v.z * v.z + v.w * v.w;
            #pragma unroll
            for (int o = 16; o > 0; o >>= 1) ss += __shfl_xor(ss, o, 64);
            float inv = rsqrtf(fmaxf(ss, 1e-16f));
            lds[(4 * li + 0) * NPAD1 + rl] = f2bf(v.x * inv);
            lds[(4 * li + 1) * NPAD1 + rl] = f2bf(v.y * inv);
            lds[(4 * li + 2) * NPAD1 + rl] = f2bf(v.z * inv);
            lds[(4 * li + 3) * NPAD1 + rl] = f2bf(v.w * inv);
        }
        {
            float4 v = ((const float4*)(k + (size_t)row * DDIM))[li];
            float ss = v.x * v.x + v.y * v.y + v.z * v.z + v.w * v.w;
            #pragma unroll
            for (int o = 16; o > 0; o >>= 1) ss += __shfl_xor(ss, o, 64);
            float inv = rsqrtf(fmaxf(ss, 1e-16f));
            lds[(128 + 4 * li + 0) * NPAD1 + rl] = f2bf(v.x * inv);
            lds[(128 + 4 * li + 1) * NPAD1 + rl] = f2bf(v.y * inv);
            lds[(128 + 4 * li + 2) * NPAD1 + rl] = f2bf(v.z * inv);
            lds[(128 + 4 * li + 3) * NPAD1 + rl] = f2bf(v.w * inv);
        }
    }
    __syncthreads();

    // phase 2: thread owns dim a; vector-read its 16 n (8 x b32, 4B-aligned,
    // 9-dword pitch -> conflict-free), store 32 B contiguous into blocked Gt.
    int a = threadIdx.x;
    union { uint_t u32[8]; uint4 v4[2]; } tb;
    #pragma unroll
    for (int t = 0; t < 8; ++t)
        tb.u32[t] = *(const uint_t*)&lds[a * NPAD1 + 2 * t];

    char* gdst = (char*)Gt + (size_t)(c * 256 + a) * (CHN * 2) + sub * 32;
    *(uint4*)(gdst)      = tb.v4[0];
    *(uint4*)(gdst + 16) = tb.v4[1];
}

// K2: partial Gram (R7-verified MFMA body, XOR-swizzled LDS). 10 pairs x
// 32 groups = 320 blocks; each block register-accumulates CPG=2 chunks
// (K=256) with double-buffered global_load_lds staging, then PLAIN-stores
// its 64x64 fp32 partial to P (no atomics -- the R2 atomic storm was the
// +10us regression).
__global__ __launch_bounds__(128, 2) void gram_a_kernel(
    const ushort_t* __restrict__ Gt, float* __restrict__ P)
{
    __shared__ ushort_t sA[2][64 * CHN];   // 2 x 16 KB
    __shared__ ushort_t sB[2][64 * CHN];   // 2 x 16 KB

    int pair = blockIdx.x >> 5;         // 0..9
    int g    = blockIdx.x & 31;         // chunk-group
    int ti, tj;
    pair_decode(pair, &ti, &tj);
    int tid = threadIdx.x;
    int c0  = g * CPG;

    auto stage = [&](int buf, int c) {
        const char* gA = (const char*)Gt + (size_t)(c * 256 + ti * 64) * (CHN * 2);
        const char* gB = (const char*)Gt + (size_t)(c * 256 + tj * 64) * (CHN * 2);
        #pragma unroll
        for (int it = 0; it < 8; ++it) {
            int ch = it * 128 + tid;               // 0..1023
            int row = ch >> 4, phys = ch & 15;
            int logical = phys ^ (row & 7);
            __builtin_amdgcn_global_load_lds(GLB_PTR(gA + row * 256 + logical * 16),
                                             LDS_PTR((char*)sA[buf] + ch * 16), 16, 0, 0);
        }
        #pragma unroll
        for (int it = 0; it < 8; ++it) {
            int ch = it * 128 + tid;
            int row = ch >> 4, phys = ch & 15;
            int logical = phys ^ (row & 7);
            __builtin_amdgcn_global_load_lds(GLB_PTR(gB + row * 256 + logical * 16),
                                             LDS_PTR((char*)sB[buf] + ch * 16), 16, 0, 0);
        }
    };

    int w    = tid >> 6;        // a-strip: rows w*32..w*32+31
    int l    = tid & 63;
    int m    = l & 15;
    int quad = l >> 4;

    floatx4 accC[2][4];
    #pragma unroll
    for (int at = 0; at < 2; ++at)
        #pragma unroll
        for (int bt = 0; bt < 4; ++bt)
            accC[at][bt] = (floatx4){0.f, 0.f, 0.f, 0.f};

    stage(0, c0);
    __syncthreads();

    #pragma unroll
    for (int j = 0; j < CPG; ++j) {
        if (j + 1 < CPG) stage((j + 1) & 1, c0 + j + 1);   // prefetch overlaps MFMA
        const ushort_t* cA = sA[j & 1];
        const ushort_t* cB = sB[j & 1];
        #pragma unroll
        for (int kp = 0; kp < 4; ++kp) {
            short8 af[2], bf[4];
            #pragma unroll
            for (int at = 0; at < 2; ++at) {
                int ra   = w * 32 + at * 16 + m;
                int phys = (kp * 4 + quad) ^ (ra & 7);
                af[at] = *(const short8*)&cA[ra * CHN + phys * 8];
            }
            #pragma unroll
            for (int bt = 0; bt < 4; ++bt) {
                int rb   = bt * 16 + m;
                int phys = (kp * 4 + quad) ^ (rb & 7);
                bf[bt] = *(const short8*)&cB[rb * CHN + phys * 8];
            }
            #pragma unroll
            for (int at = 0; at < 2; ++at)
                #pragma unroll
                for (int bt = 0; bt < 4; ++bt)
                    accC[at][bt] = __builtin_amdgcn_mfma_f32_16x16x32_bf16(af[at], bf[bt], accC[at][bt], 0, 0, 0);
        }
        __syncthreads();
    }

    // write 64x64 fp32 partial (C layout: col=m, row=quad*4+reg)
    float* pt = P + ((size_t)pair * NGRP + g) * 4096;
    #pragma unroll
    for (int at = 0; at < 2; ++at)
        #pragma unroll
        for (int bt = 0; bt < 4; ++bt)
            #pragma unroll
            for (int r = 0; r < 4; ++r) {
                int row = w * 32 + at * 16 + quad * 4 + r;
                int col = bt * 16 + m;
                pt[row * 64 + col] = accC[at][bt][r];
            }
}

// K3: reduce partials over 32 groups, weight (sign x symmetry), square,
// fp64 accumulate; LAST block finalizes into out. (R7-proven version.)
__global__ __launch_bounds__(256) void gram_b_kernel(
    const float* __restrict__ P, double* acc, uint_t* counter, float* out)
{
    __shared__ float wsum[4];
    int e    = blockIdx.x * 256 + threadIdx.x;   // 0..40959
    int pair = e >> 12;
    int idx  = e & 4095;

    float s = 0.f;
    #pragma unroll
    for (int g = 0; g < NGRP; ++g)
        s += P[((size_t)pair * NGRP + g) * 4096 + idx];

    int ti, tj;
    pair_decode(pair, &ti, &tj);
    float wgt = ((ti < 2) == (tj < 2)) ? 1.f : -1.f;
    if (ti != tj) wgt *= 2.f;                    // symmetric tile counted twice
    float v = wgt * s * s;

    int w = threadIdx.x >> 6, l = threadIdx.x & 63;
    #pragma unroll
    for (int o = 32; o > 0; o >>= 1) v += __shfl_xor(v, o, 64);
    if (l == 0) wsum[w] = v;
    __syncthreads();
    if (threadIdx.x == 0) {
        double t = (double)wsum[0] + (double)wsum[1] + (double)wsum[2] + (double)wsum[3];
        atomicAdd(acc, t);
        __threadfence();
        uint_t old = atomicAdd(counter, 1u);
        if (old == GB_BLOCKS - 1) {
            double total = atomicAdd(acc, 0.0);  // coherent read of final sum
            out[0] = (float)(total * (1.0 / ((double)NROWS * (double)(NROWS - 1))));
        }
    }
}

extern "C" void kernel_launch(void* const* d_in, const int* in_sizes, int n_in,
                              void* d_out, int out_size, void* d_ws, size_t ws_size,
                              hipStream_t stream) {
    const float* q = (const float*)d_in[0];
    const float* k = (const float*)d_in[1];
    float* out = (float*)d_out;

    double*   acc = (double*)d_ws;
    uint_t*   cnt = (uint_t*)((char*)d_ws + 64);
    ushort_t* Gt  = (ushort_t*)((char*)d_ws + 256);                    // 4 MB blocked
    float*    P   = (float*)((char*)d_ws + 256 + (size_t)NKCH * 256 * CHN * 2); // 5.25 MB

    norm_t_kernel<<<NROWS / 16, 256, 0, stream>>>(q, k, Gt, acc, cnt);
    gram_a_kernel<<<K2_BLOCKS, 128, 0, stream>>>(Gt, P);
    gram_b_kernel<<<GB_BLOCKS, 256, 0, stream>>>(P, acc, cnt, out);
}

// Round 4
// 71.627 us; speedup vs baseline: 1.1773x; 1.0099x over previous
//
#include <hip/hip_runtime.h>
#include <hip/hip_bf16.h>

#define NROWS 8192
#define DDIM  128
#define NKCH  64                    // n-chunks of 128
#define CHN   128                   // n per chunk
#define NPAIR 10                    // triangular (ti<=tj) over 4 dim-groups of 64
#define NGRP  16                    // chunk-groups per pair
#define CPG   4                     // chunks accumulated per block (K=512)
#define K2_BLOCKS (NPAIR * NGRP)    // 160
#define GB_BLOCKS 160               // gram_b grid (10*4096/256)
#define NPAD1 18                    // norm LDS column-major pitch in shorts (9 dwords, coprime 32)

typedef unsigned short ushort_t;
typedef unsigned int   uint_t;
typedef __attribute__((ext_vector_type(8))) short short8;
typedef __attribute__((ext_vector_type(4))) float floatx4;

#define LDS_PTR(p) ((__attribute__((address_space(3))) void*)(p))
#define GLB_PTR(p) ((const __attribute__((address_space(1))) void*)(p))

// round-to-nearest-even fp32 -> bf16 bits
static __device__ inline ushort_t f2bf(float f) {
    union { float f; uint_t u; } a; a.f = f;
    uint_t u = a.u + 0x7fffu + ((a.u >> 16) & 1u);
    return (ushort_t)(u >> 16);
}

// decode triangular pair p -> (ti,tj), ti<=tj over 4 groups
static __device__ inline void pair_decode(int p, int* ti, int* tj) {
    int i = 0, len = 4;
    while (p >= len) { p -= len; len--; i++; }
    *ti = i; *tj = i + p;
}

// K1: row-normalize q,k -> bf16, write BLOCKED transposed Gt:
// layout [c:64][dim:256][n:128], dim<128 = Qn, dim>=128 = Kn.
// 512 blocks x 16 n-rows (2 blocks/CU -> 2x latency hiding vs 256-block ver).
__global__ __launch_bounds__(256) void norm_t_kernel(
    const float* __restrict__ q, const float* __restrict__ k,
    ushort_t* __restrict__ Gt, double* acc, uint_t* counter)
{
    __shared__ ushort_t lds[256 * NPAD1];   // 9.2 KB: [dim][n-local 16]
    if (blockIdx.x == 0 && threadIdx.x == 0) { *acc = 0.0; *counter = 0u; }

    int b   = blockIdx.x;        // 512 blocks x 16 rows
    int c   = b >> 3;            // chunk 0..63
    int sub = b & 7;             // 16-row eighth of the chunk
    int w   = threadIdx.x >> 6;
    int l   = threadIdx.x & 63;
    int h   = l >> 5;            // half-wave: row parity
    int li  = l & 31;            // lane in half: 4 dims each

    #pragma unroll
    for (int i = 0; i < 2; ++i) {
        int rl  = i * 8 + w * 2 + h;             // local n-row 0..15
        int row = b * 16 + rl;
        {
            float4 v = ((const float4*)(q + (size_t)row * DDIM))[li];
            float ss = v.x * v.x + v.y * v.y + v.z * v.z + v.w * v.w;
            #pragma unroll
            for (int o = 16; o > 0; o >>= 1) ss += __shfl_xor(ss, o, 64);
            float inv = rsqrtf(fmaxf(ss, 1e-16f));
            lds[(4 * li + 0) * NPAD1 + rl] = f2bf(v.x * inv);
            lds[(4 * li + 1) * NPAD1 + rl] = f2bf(v.y * inv);
            lds[(4 * li + 2) * NPAD1 + rl] = f2bf(v.z * inv);
            lds[(4 * li + 3) * NPAD1 + rl] = f2bf(v.w * inv);
        }
        {
            float4 v = ((const float4*)(k + (size_t)row * DDIM))[li];
            float ss = v.x * v.x + v.y * v.y + v.z * v.z + v.w * v.w;
            #pragma unroll
            for (int o = 16; o > 0; o >>= 1) ss += __shfl_xor(ss, o, 64);
            float inv = rsqrtf(fmaxf(ss, 1e-16f));
            lds[(128 + 4 * li + 0) * NPAD1 + rl] = f2bf(v.x * inv);
            lds[(128 + 4 * li + 1) * NPAD1 + rl] = f2bf(v.y * inv);
            lds[(128 + 4 * li + 2) * NPAD1 + rl] = f2bf(v.z * inv);
            lds[(128 + 4 * li + 3) * NPAD1 + rl] = f2bf(v.w * inv);
        }
    }
    __syncthreads();

    // phase 2: thread owns dim a; vector-read its 16 n (8 x b32, 4B-aligned,
    // 9-dword pitch -> conflict-free), store 32 B contiguous into blocked Gt.
    int a = threadIdx.x;
    union { uint_t u32[8]; uint4 v4[2]; } tb;
    #pragma unroll
    for (int t = 0; t < 8; ++t)
        tb.u32[t] = *(const uint_t*)&lds[a * NPAD1 + 2 * t];

    char* gdst = (char*)Gt + (size_t)(c * 256 + a) * (CHN * 2) + sub * 32;
    *(uint4*)(gdst)      = tb.v4[0];
    *(uint4*)(gdst + 16) = tb.v4[1];
}

// K2: partial Gram (R7-verified MFMA body, XOR-swizzled LDS). 10 pairs x
// 16 groups = 160 blocks; each block register-accumulates CPG=4 chunks
// (K=512) with double-buffered global_load_lds staging, then PLAIN-stores
// its 64x64 fp32 partial to P (no atomics -- the R2 atomic storm was the
// +10us regression; this K2 geometry itself ran correctly in R2).
__global__ __launch_bounds__(128, 2) void gram_a_kernel(
    const ushort_t* __restrict__ Gt, float* __restrict__ P)
{
    __shared__ ushort_t sA[2][64 * CHN];   // 2 x 16 KB
    __shared__ ushort_t sB[2][64 * CHN];   // 2 x 16 KB

    int pair = blockIdx.x >> 4;         // 0..9
    int g    = blockIdx.x & 15;         // chunk-group
    int ti, tj;
    pair_decode(pair, &ti, &tj);
    int tid = threadIdx.x;
    int c0  = g * CPG;

    auto stage = [&](int buf, int c) {
        const char* gA = (const char*)Gt + (size_t)(c * 256 + ti * 64) * (CHN * 2);
        const char* gB = (const char*)Gt + (size_t)(c * 256 + tj * 64) * (CHN * 2);
        #pragma unroll
        for (int it = 0; it < 8; ++it) {
            int ch = it * 128 + tid;               // 0..1023
            int row = ch >> 4, phys = ch & 15;
            int logical = phys ^ (row & 7);
            __builtin_amdgcn_global_load_lds(GLB_PTR(gA + row * 256 + logical * 16),
                                             LDS_PTR((char*)sA[buf] + ch * 16), 16, 0, 0);
        }
        #pragma unroll
        for (int it = 0; it < 8; ++it) {
            int ch = it * 128 + tid;
            int row = ch >> 4, phys = ch & 15;
            int logical = phys ^ (row & 7);
            __builtin_amdgcn_global_load_lds(GLB_PTR(gB + row * 256 + logical * 16),
                                             LDS_PTR((char*)sB[buf] + ch * 16), 16, 0, 0);
        }
    };

    int w    = tid >> 6;        // a-strip: rows w*32..w*32+31
    int l    = tid & 63;
    int m    = l & 15;
    int quad = l >> 4;

    floatx4 accC[2][4];
    #pragma unroll
    for (int at = 0; at < 2; ++at)
        #pragma unroll
        for (int bt = 0; bt < 4; ++bt)
            accC[at][bt] = (floatx4){0.f, 0.f, 0.f, 0.f};

    stage(0, c0);
    __syncthreads();

    #pragma unroll
    for (int j = 0; j < CPG; ++j) {
        if (j + 1 < CPG) stage((j + 1) & 1, c0 + j + 1);   // prefetch overlaps MFMA
        const ushort_t* cA = sA[j & 1];
        const ushort_t* cB = sB[j & 1];
        #pragma unroll
        for (int kp = 0; kp < 4; ++kp) {
            short8 af[2], bf[4];
            #pragma unroll
            for (int at = 0; at < 2; ++at) {
                int ra   = w * 32 + at * 16 + m;
                int phys = (kp * 4 + quad) ^ (ra & 7);
                af[at] = *(const short8*)&cA[ra * CHN + phys * 8];
            }
            #pragma unroll
            for (int bt = 0; bt < 4; ++bt) {
                int rb   = bt * 16 + m;
                int phys = (kp * 4 + quad) ^ (rb & 7);
                bf[bt] = *(const short8*)&cB[rb * CHN + phys * 8];
            }
            #pragma unroll
            for (int at = 0; at < 2; ++at)
                #pragma unroll
                for (int bt = 0; bt < 4; ++bt)
                    accC[at][bt] = __builtin_amdgcn_mfma_f32_16x16x32_bf16(af[at], bf[bt], accC[at][bt], 0, 0, 0);
        }
        __syncthreads();
    }

    // write 64x64 fp32 partial (C layout: col=m, row=quad*4+reg)
    float* pt = P + ((size_t)pair * NGRP + g) * 4096;
    #pragma unroll
    for (int at = 0; at < 2; ++at)
        #pragma unroll
        for (int bt = 0; bt < 4; ++bt)
            #pragma unroll
            for (int r = 0; r < 4; ++r) {
                int row = w * 32 + at * 16 + quad * 4 + r;
                int col = bt * 16 + m;
                pt[row * 64 + col] = accC[at][bt][r];
            }
}

// K3: reduce partials over 16 groups, weight (sign x symmetry), square,
// fp64 accumulate; LAST block finalizes into out. (R7-proven version.)
__global__ __launch_bounds__(256) void gram_b_kernel(
    const float* __restrict__ P, double* acc, uint_t* counter, float* out)
{
    __shared__ float wsum[4];
    int e    = blockIdx.x * 256 + threadIdx.x;   // 0..40959
    int pair = e >> 12;
    int idx  = e & 4095;

    float s = 0.f;
    #pragma unroll
    for (int g = 0; g < NGRP; ++g)
        s += P[((size_t)pair * NGRP + g) * 4096 + idx];

    int ti, tj;
    pair_decode(pair, &ti, &tj);
    float wgt = ((ti < 2) == (tj < 2)) ? 1.f : -1.f;
    if (ti != tj) wgt *= 2.f;                    // symmetric tile counted twice
    float v = wgt * s * s;

    int w = threadIdx.x >> 6, l = threadIdx.x & 63;
    #pragma unroll
    for (int o = 32; o > 0; o >>= 1) v += __shfl_xor(v, o, 64);
    if (l == 0) wsum[w] = v;
    __syncthreads();
    if (threadIdx.x == 0) {
        double t = (double)wsum[0] + (double)wsum[1] + (double)wsum[2] + (double)wsum[3];
        atomicAdd(acc, t);
        __threadfence();
        uint_t old = atomicAdd(counter, 1u);
        if (old == GB_BLOCKS - 1) {
            double total = atomicAdd(acc, 0.0);  // coherent read of final sum
            out[0] = (float)(total * (1.0 / ((double)NROWS * (double)(NROWS - 1))));
        }
    }
}

extern "C" void kernel_launch(void* const* d_in, const int* in_sizes, int n_in,
                              void* d_out, int out_size, void* d_ws, size_t ws_size,
                              hipStream_t stream) {
    const float* q = (const float*)d_in[0];
    const float* k = (const float*)d_in[1];
    float* out = (float*)d_out;

    double*   acc = (double*)d_ws;
    uint_t*   cnt = (uint_t*)((char*)d_ws + 64);
    ushort_t* Gt  = (ushort_t*)((char*)d_ws + 256);                    // 4 MB blocked
    float*    P   = (float*)((char*)d_ws + 256 + (size_t)NKCH * 256 * CHN * 2); // 2.62 MB

    norm_t_kernel<<<NROWS / 16, 256, 0, stream>>>(q, k, Gt, acc, cnt);
    gram_a_kernel<<<K2_BLOCKS, 128, 0, stream>>>(Gt, P);
    gram_b_kernel<<<GB_BLOCKS, 256, 0, stream>>>(P, acc, cnt, out);
}